// Round 1
// baseline (1443.678 us; speedup 1.0000x reference)
//
#include <hip/hip_runtime.h>
#include <hip/hip_bf16.h>

#define NPIX 16384   // H*W
#define NC   48      // DIM

// ---------------- kernel 1/6: pointwise conv  out[o][p] = sum_c w[o][c]*in[c][p]
__global__ __launch_bounds__(256) void k_pointwise(const float* __restrict__ in,
                                                   const float* __restrict__ w,
                                                   float* __restrict__ out) {
  int p = blockIdx.x * 256 + threadIdx.x;
  int og = blockIdx.y * 16;
  __shared__ float wl[16][NC];
  for (int i = threadIdx.x; i < 16 * NC; i += 256)
    wl[i / NC][i % NC] = w[(og + i / NC) * NC + i % NC];
  __syncthreads();
  float acc[16];
#pragma unroll
  for (int j = 0; j < 16; ++j) acc[j] = 0.f;
  for (int c = 0; c < NC; ++c) {
    float xv = in[c * NPIX + p];
#pragma unroll
    for (int j = 0; j < 16; ++j) acc[j] += xv * wl[j][c];
  }
#pragma unroll
  for (int j = 0; j < 16; ++j) out[(og + j) * NPIX + p] = acc[j];
}

// ---------------- kernel 2: depthwise 3x3, SAME zero pad (cross-correlation, no flip)
__global__ __launch_bounds__(256) void k_dwconv(const float* __restrict__ in,
                                                const float* __restrict__ w,
                                                float* __restrict__ out) {
  int p = blockIdx.x * 256 + threadIdx.x;
  int o = blockIdx.y;
  int y = p >> 7, xx = p & 127;
  const float* base = in + o * NPIX;
  const float* wt = w + o * 9;
  float acc = 0.f;
#pragma unroll
  for (int dy = -1; dy <= 1; ++dy)
#pragma unroll
    for (int dx = -1; dx <= 1; ++dx) {
      int yy = y + dy, xc = xx + dx;
      if (yy >= 0 && yy < 128 && xc >= 0 && xc < 128)
        acc += wt[(dy + 1) * 3 + (dx + 1)] * base[yy * 128 + xc];
    }
  out[o * NPIX + p] = acc;
}

// ---------------- kernel 3: per-token l2norm of q,k; q scaled by temperature
__global__ __launch_bounds__(256) void k_norm(const float* __restrict__ dwq,
                                              const float* __restrict__ temp,
                                              float* __restrict__ qn,
                                              float* __restrict__ kn) {
  int p = blockIdx.x * 256 + threadIdx.x;
  float t = temp[0];
  float sq = 0.f, sk = 0.f;
  for (int c = 0; c < NC; ++c) {
    float a = dwq[c * NPIX + p];
    float b = dwq[(NC + c) * NPIX + p];
    sq += a * a;
    sk += b * b;
  }
  float rq = t / fmaxf(sqrtf(sq), 1e-12f);
  float rk = 1.0f / fmaxf(sqrtf(sk), 1e-12f);
  for (int c = 0; c < NC; ++c) {
    qn[c * NPIX + p] = dwq[c * NPIX + p] * rq;
    kn[c * NPIX + p] = dwq[(NC + c) * NPIX + p] * rk;
  }
}

// ---------------- kernel 4: fused attention, no-rescale softmax (|S|<=t)
// grid (128 query-tiles, 2 key-halves), 256 threads.
// Writes partial num [2][48][16384] (channel-major) and den [2][16384].
__global__ __launch_bounds__(256) void k_attn(const float* __restrict__ qn,
                                              const float* __restrict__ kn,
                                              const float* __restrict__ vg,
                                              float* __restrict__ num,
                                              float* __restrict__ den) {
  __shared__ float Qt[NC][132];    // [c][n_local]
  __shared__ float Kt[NC][132];    // [c][m_local]
  __shared__ float Vl[128][53];    // [m_local][c]
  __shared__ float Pl[128][132];   // [n_local][m_local]
  int tid = threadIdx.x;
  int qb = blockIdx.x, kh = blockIdx.y;
  int n0 = qb * 128;

  // stage Q tile once (channel-major global -> same layout LDS, coalesced)
  for (int i = tid; i < NC * 32; i += 256) {
    int c = i >> 5, ch = (i & 31) << 2;
    *(float4*)&Qt[c][ch] = *(const float4*)&qn[c * NPIX + n0 + ch];
  }

  int tn = tid >> 4, tm = tid & 15;   // S-phase mapping: n=8tn+a, m=8tm+b
  int tn2 = tid & 15, tc = tid >> 4;  // PV mapping: n=tn2+16j (interleaved), c=3tc+cc

  float o_acc[8][3];
  float den8[8];
#pragma unroll
  for (int a = 0; a < 8; ++a) {
    den8[a] = 0.f;
    o_acc[a][0] = o_acc[a][1] = o_acc[a][2] = 0.f;
  }

  for (int it = 0; it < 64; ++it) {
    int m0 = kh * 8192 + it * 128;
    __syncthreads();  // prev PV done reading Vl/Pl, prev S done reading Kt
    for (int i = tid; i < NC * 32; i += 256) {
      int c = i >> 5, ch = (i & 31) << 2;
      *(float4*)&Kt[c][ch] = *(const float4*)&kn[c * NPIX + m0 + ch];
    }
    for (int i = tid; i < NC * 32; i += 256) {
      int c = i >> 5, ch = (i & 31) << 2;
      float4 f = *(const float4*)&vg[c * NPIX + m0 + ch];
      Vl[ch + 0][c] = f.x;
      Vl[ch + 1][c] = f.y;
      Vl[ch + 2][c] = f.z;
      Vl[ch + 3][c] = f.w;
    }
    __syncthreads();

    // S = (t*qhat)^T khat  (8x8 register block per thread)
    float s[8][8];
#pragma unroll
    for (int a = 0; a < 8; ++a)
#pragma unroll
      for (int b = 0; b < 8; ++b) s[a][b] = 0.f;
#pragma unroll 4
    for (int c = 0; c < NC; ++c) {
      float4 q0 = *(float4*)&Qt[c][tn * 8];
      float4 q1 = *(float4*)&Qt[c][tn * 8 + 4];
      float4 k0 = *(float4*)&Kt[c][tm * 8];
      float4 k1 = *(float4*)&Kt[c][tm * 8 + 4];
      float qv[8] = {q0.x, q0.y, q0.z, q0.w, q1.x, q1.y, q1.z, q1.w};
      float kv[8] = {k0.x, k0.y, k0.z, k0.w, k1.x, k1.y, k1.z, k1.w};
#pragma unroll
      for (int a = 0; a < 8; ++a)
#pragma unroll
        for (int b = 0; b < 8; ++b) s[a][b] += qv[a] * kv[b];
    }
    // exp (no max subtraction needed: |S| <= t), accumulate den, park P in LDS
#pragma unroll
    for (int a = 0; a < 8; ++a) {
#pragma unroll
      for (int b = 0; b < 8; ++b) {
        float e = __expf(s[a][b]);
        s[a][b] = e;
        den8[a] += e;
      }
      *(float4*)&Pl[tn * 8 + a][tm * 8] = make_float4(s[a][0], s[a][1], s[a][2], s[a][3]);
      *(float4*)&Pl[tn * 8 + a][tm * 8 + 4] = make_float4(s[a][4], s[a][5], s[a][6], s[a][7]);
    }
    __syncthreads();

    // O += P @ V   (n interleaved stride-16 so P-row reads spread banks)
#pragma unroll 2
    for (int mq = 0; mq < 32; ++mq) {
      float4 p4[8];
#pragma unroll
      for (int j = 0; j < 8; ++j) p4[j] = *(float4*)&Pl[tn2 + 16 * j][mq * 4];
      float vv[4][3];
#pragma unroll
      for (int e = 0; e < 4; ++e)
#pragma unroll
        for (int cc = 0; cc < 3; ++cc) vv[e][cc] = Vl[mq * 4 + e][tc * 3 + cc];
#pragma unroll
      for (int j = 0; j < 8; ++j)
#pragma unroll
        for (int cc = 0; cc < 3; ++cc)
          o_acc[j][cc] += p4[j].x * vv[0][cc] + p4[j].y * vv[1][cc] +
                          p4[j].z * vv[2][cc] + p4[j].w * vv[3][cc];
    }
  }

  // write partial numerator, channel-major [2][48][16384]
#pragma unroll
  for (int j = 0; j < 8; ++j)
#pragma unroll
    for (int cc = 0; cc < 3; ++cc)
      num[(kh * NC + tc * 3 + cc) * NPIX + n0 + tn2 + 16 * j] = o_acc[j][cc];

  // reduce den over tm groups via LDS scratch (reuse Kt)
  __syncthreads();
  float* dl = &Kt[0][0];
#pragma unroll
  for (int a = 0; a < 8; ++a) dl[(tn * 8 + a) * 17 + tm] = den8[a];
  __syncthreads();
  if (tid < 128) {
    float ss = 0.f;
#pragma unroll
    for (int u = 0; u < 16; ++u) ss += dl[tid * 17 + u];
    den[kh * NPIX + n0 + tid] = ss;
  }
}

// ---------------- kernel 5: combine key-halves and divide -> tokT [c][p]
__global__ __launch_bounds__(256) void k_combine(const float* __restrict__ num,
                                                 const float* __restrict__ den,
                                                 float* __restrict__ tokT) {
  int p = blockIdx.x * 256 + threadIdx.x;
  int c = blockIdx.y;
  float d = den[p] + den[NPIX + p];
  float ns = num[c * NPIX + p] + num[(NC + c) * NPIX + p];
  tokT[c * NPIX + p] = ns / d;
}

extern "C" void kernel_launch(void* const* d_in, const int* in_sizes, int n_in,
                              void* d_out, int out_size, void* d_ws, size_t ws_size,
                              hipStream_t stream) {
  const float* x      = (const float*)d_in[0];
  const float* qkv_w  = (const float*)d_in[1];
  const float* dw_w   = (const float*)d_in[2];
  const float* proj_w = (const float*)d_in[3];
  const float* temp   = (const float*)d_in[4];
  float* ws = (float*)d_ws;

  // workspace layout (floats); total ~25.3 MB
  float* qkv  = ws;                  // [144][16384]
  float* dwq  = ws + 2359296;        // [144][16384]
  float* qn   = ws;                  // reuse qkv region (dead after dwconv)
  float* kn   = ws + 786432;
  float* tokT = ws + 1572864;
  float* num  = ws + 4718592;        // [2][48][16384]
  float* den  = ws + 6291456;        // [2][16384]
  const float* vg = dwq + 96 * NPIX; // v = dw output channels 96..143

  k_pointwise<<<dim3(64, 9), 256, 0, stream>>>(x, qkv_w, qkv);
  k_dwconv<<<dim3(64, 144), 256, 0, stream>>>(qkv, dw_w, dwq);
  k_norm<<<dim3(64, 1), 256, 0, stream>>>(dwq, temp, qn, kn);
  k_attn<<<dim3(128, 2), 256, 0, stream>>>(qn, kn, vg, num, den);
  k_combine<<<dim3(64, 48), 256, 0, stream>>>(num, den, tokT);
  k_pointwise<<<dim3(64, 3), 256, 0, stream>>>(tokT, proj_w, (float*)d_out);
}

// Round 2
// 172.558 us; speedup vs baseline: 8.3663x; 8.3663x over previous
//
#include <hip/hip_runtime.h>
#include <hip/hip_bf16.h>

#define NPIX 16384   // H*W
#define NC   48      // DIM

typedef __attribute__((ext_vector_type(16))) float f32x16;
typedef __attribute__((ext_vector_type(8))) short short8v;
typedef __attribute__((ext_vector_type(8))) unsigned short ushort8v;
typedef __attribute__((ext_vector_type(2))) unsigned int uint2v;

static __device__ __forceinline__ unsigned short f2bf(float x) {
  union { float f; unsigned u; } v; v.f = x;
  unsigned r = v.u + 0x7fffu + ((v.u >> 16) & 1u);
  return (unsigned short)(r >> 16);
}

// ---------------- kernel 1: pointwise conv  out[o][p] = sum_c w[o][c]*in[c][p]
__global__ __launch_bounds__(256) void k_pointwise(const float* __restrict__ in,
                                                   const float* __restrict__ w,
                                                   float* __restrict__ out) {
  int p = blockIdx.x * 256 + threadIdx.x;
  int og = blockIdx.y * 16;
  __shared__ float wl[16][NC];
  for (int i = threadIdx.x; i < 16 * NC; i += 256)
    wl[i / NC][i % NC] = w[(og + i / NC) * NC + i % NC];
  __syncthreads();
  float acc[16];
#pragma unroll
  for (int j = 0; j < 16; ++j) acc[j] = 0.f;
  for (int c = 0; c < NC; ++c) {
    float xv = in[c * NPIX + p];
#pragma unroll
    for (int j = 0; j < 16; ++j) acc[j] += xv * wl[j][c];
  }
#pragma unroll
  for (int j = 0; j < 16; ++j) out[(og + j) * NPIX + p] = acc[j];
}

// ---------------- kernel 2: depthwise 3x3, SAME zero pad (cross-correlation)
__global__ __launch_bounds__(256) void k_dwconv(const float* __restrict__ in,
                                                const float* __restrict__ w,
                                                float* __restrict__ out) {
  int p = blockIdx.x * 256 + threadIdx.x;
  int o = blockIdx.y;
  int y = p >> 7, xx = p & 127;
  const float* base = in + o * NPIX;
  const float* wt = w + o * 9;
  float acc = 0.f;
#pragma unroll
  for (int dy = -1; dy <= 1; ++dy)
#pragma unroll
    for (int dx = -1; dx <= 1; ++dx) {
      int yy = y + dy, xc = xx + dx;
      if (yy >= 0 && yy < 128 && xc >= 0 && xc < 128)
        acc += wt[(dy + 1) * 3 + (dx + 1)] * base[yy * 128 + xc];
    }
  out[o * NPIX + p] = acc;
}

// ---------------- kernel 3: l2norm q,k (q scaled by temperature) -> bf16
// qn,kn token-major [p][48]; v cast to bf16 channel-major vb[c][p]
__global__ __launch_bounds__(256) void k_norm(const float* __restrict__ dwq,
                                              const float* __restrict__ temp,
                                              unsigned short* __restrict__ qn,
                                              unsigned short* __restrict__ kn,
                                              unsigned short* __restrict__ vb) {
  int p = blockIdx.x * 256 + threadIdx.x;
  float t = temp[0];
  float qv[48], kv[48];
  float sq = 0.f, sk = 0.f;
#pragma unroll
  for (int c = 0; c < 48; ++c) {
    qv[c] = dwq[c * NPIX + p];
    kv[c] = dwq[(48 + c) * NPIX + p];
    sq += qv[c] * qv[c];
    sk += kv[c] * kv[c];
  }
  float rq = t / fmaxf(sqrtf(sq), 1e-12f);
  float rk = 1.f / fmaxf(sqrtf(sk), 1e-12f);
  unsigned short qb[48], kb[48];
#pragma unroll
  for (int c = 0; c < 48; ++c) {
    qb[c] = f2bf(qv[c] * rq);
    kb[c] = f2bf(kv[c] * rk);
  }
#pragma unroll
  for (int j = 0; j < 6; ++j) {
    *(ushort8v*)(qn + p * 48 + j * 8) = *(ushort8v*)&qb[j * 8];
    *(ushort8v*)(kn + p * 48 + j * 8) = *(ushort8v*)&kb[j * 8];
  }
#pragma unroll
  for (int c = 0; c < 48; ++c)
    vb[c * NPIX + p] = f2bf(dwq[(96 + c) * NPIX + p]);
}

// ---------------- kernel 4: MFMA attention (32x32x16 bf16)
// grid (128 q-blocks, 4 key-splits), 256 thr (4 waves x 32 q-rows).
// S' = mfma(K, Q) -> lane-local softmax (|S|<=t, no max), P repacked via
// cvt_pk_bf16 + permlane32_swap, O = mfma(P, V) with ones-channel c=48 = den.
// num layout: [4][49][16384] channel-major, c=48 is the denominator row.
__global__ __launch_bounds__(256) void k_attn(const unsigned short* __restrict__ qn,
                                              const unsigned short* __restrict__ kn,
                                              const unsigned short* __restrict__ vb,
                                              float* __restrict__ num) {
  __shared__ __align__(16) char smem[28672];  // K: 128x96B @0, Vt: 64x256B @12288
  const int tid = threadIdx.x;
  const int lane = tid & 63, wid = tid >> 6;
  const int l31 = lane & 31, lh = lane >> 5;
  const int qb = blockIdx.x, ks = blockIdx.y;
  const int qbase = qb * 128 + wid * 32;

  // Q fragments (B operand): lane holds q-row qbase+l31, channels s*16+lh*8..+8
  short8v qf[3];
#pragma unroll
  for (int s = 0; s < 3; ++s)
    qf[s] = *(const short8v*)(qn + (qbase + l31) * 48 + s * 16 + lh * 8);

  f32x16 oacc0, oacc1;
#pragma unroll
  for (int r = 0; r < 16; ++r) { oacc0[r] = 0.f; oacc1[r] = 0.f; }

  // Vt rows 48..63: row 48 = ones (den), rest zero. Written once, never staged over.
  for (int i = tid; i < 256; i += 256) {
    int c = 48 + (i >> 4), kp = i & 15;
    unsigned short val = (c == 48) ? (unsigned short)0x3F80 : (unsigned short)0;
    ushort8v vv = {val, val, val, val, val, val, val, val};
    *(ushort8v*)(smem + 12288 + ((c * 256 + kp * 16) ^ ((c & 7) << 4))) = vv;
  }

  for (int st = 0; st < 32; ++st) {
    const int m0 = ks * 4096 + st * 128;
    __syncthreads();
    // stage K tile: 128 keys x 48ch bf16, token-major, XOR-swizzled
#pragma unroll
    for (int i = 0; i < 3; ++i) {
      int chunk = tid + 256 * i;
      int key = chunk / 6, part = chunk - key * 6;
      short8v kv = *(const short8v*)(kn + (m0 + key) * 48 + part * 8);
      *(short8v*)(smem + ((key * 96 + part * 16) ^ ((key & 7) << 4))) = kv;
    }
    // stage V tile: 48ch x 128 keys bf16, channel-major, XOR-swizzled
#pragma unroll
    for (int i = 0; i < 3; ++i) {
      int chunk = tid + 256 * i;
      int c = chunk >> 4, kp = chunk & 15;
      short8v vv = *(const short8v*)(vb + c * NPIX + m0 + kp * 8);
      *(short8v*)(smem + 12288 + ((c * 256 + kp * 16) ^ ((c & 7) << 4))) = vv;
    }
    __syncthreads();

#pragma unroll
    for (int kb = 0; kb < 128; kb += 32) {
      // S' = K . Q^T : D[key][q], lane: col q = l31, rows = 16 keys
      f32x16 sacc;
#pragma unroll
      for (int r = 0; r < 16; ++r) sacc[r] = 0.f;
#pragma unroll
      for (int s = 0; s < 3; ++s) {
        int key = kb + l31;
        short8v kf = *(const short8v*)(smem +
            ((key * 96 + s * 32 + lh * 16) ^ ((key & 7) << 4)));
        sacc = __builtin_amdgcn_mfma_f32_32x32x16_bf16(kf, qf[s], sacc, 0, 0, 0);
      }
      float p[16];
#pragma unroll
      for (int r = 0; r < 16; ++r) p[r] = __expf(sacc[r]);
      // build PV A-fragments: cvt_pk pairs then swap halves across lane 32 boundary
#pragma unroll
      for (int h = 0; h < 2; ++h) {
        unsigned a0, a1, b0, b1;
        asm("v_cvt_pk_bf16_f32 %0, %1, %2" : "=v"(a0) : "v"(p[8 * h + 0]), "v"(p[8 * h + 1]));
        asm("v_cvt_pk_bf16_f32 %0, %1, %2" : "=v"(a1) : "v"(p[8 * h + 2]), "v"(p[8 * h + 3]));
        asm("v_cvt_pk_bf16_f32 %0, %1, %2" : "=v"(b0) : "v"(p[8 * h + 4]), "v"(p[8 * h + 5]));
        asm("v_cvt_pk_bf16_f32 %0, %1, %2" : "=v"(b1) : "v"(p[8 * h + 6]), "v"(p[8 * h + 7]));
        uint2v s0 = __builtin_amdgcn_permlane32_swap(a0, b0, false, false);
        uint2v s1 = __builtin_amdgcn_permlane32_swap(a1, b1, false, false);
        union { unsigned u[4]; short8v v; } pa;
        pa.u[0] = s0[0]; pa.u[1] = s1[0]; pa.u[2] = s0[1]; pa.u[3] = s1[1];
        int kbase = kb + 16 * h + 8 * lh;
        short8v vf0 = *(const short8v*)(smem + 12288 +
            ((l31 * 256 + kbase * 2) ^ ((l31 & 7) << 4)));
        oacc0 = __builtin_amdgcn_mfma_f32_32x32x16_bf16(pa.v, vf0, oacc0, 0, 0, 0);
        int c1 = 32 + l31;
        short8v vf1 = *(const short8v*)(smem + 12288 +
            ((c1 * 256 + kbase * 2) ^ ((c1 & 7) << 4)));
        oacc1 = __builtin_amdgcn_mfma_f32_32x32x16_bf16(pa.v, vf1, oacc1, 0, 0, 0);
      }
    }
  }

  // transpose O through LDS (per-wave [32 q][52 c] region), then coalesced store
  __syncthreads();
  float* ot = (float*)(smem) + wid * (32 * 52);
#pragma unroll
  for (int r = 0; r < 16; ++r) {
    int q = (r & 3) + 8 * (r >> 2) + 4 * lh;
    ot[q * 52 + l31] = oacc0[r];
    if (l31 < 17) ot[q * 52 + 32 + l31] = oacc1[r];
  }
  __syncthreads();
  for (int idx = lane; idx < 49 * 32; idx += 64) {
    int q = idx & 31, c = idx >> 5;
    num[((ks * 49 + c) << 14) + qbase + q] = ot[q * 52 + c];
  }
}

// ---------------- kernel 5: combine key-splits and divide -> tokT [c][p]
__global__ __launch_bounds__(256) void k_combine(const float* __restrict__ num,
                                                 float* __restrict__ tokT) {
  int p = blockIdx.x * 256 + threadIdx.x;
  int c = blockIdx.y;
  float d = 0.f, s = 0.f;
#pragma unroll
  for (int ks = 0; ks < 4; ++ks) {
    d += num[(ks * 49 + 48) * NPIX + p];
    s += num[(ks * 49 + c) * NPIX + p];
  }
  tokT[c * NPIX + p] = s / d;
}

extern "C" void kernel_launch(void* const* d_in, const int* in_sizes, int n_in,
                              void* d_out, int out_size, void* d_ws, size_t ws_size,
                              hipStream_t stream) {
  const float* x      = (const float*)d_in[0];
  const float* qkv_w  = (const float*)d_in[1];
  const float* dw_w   = (const float*)d_in[2];
  const float* proj_w = (const float*)d_in[3];
  const float* temp   = (const float*)d_in[4];
  float* ws = (float*)d_ws;

  // workspace (floats), peak 20.7 MB:
  //   qkv  [144][16384] @ 0          (dead after dwconv)
  //   dwq  [144][16384] @ 2359296    (dead after norm)
  //   qn/kn bf16 [16384][48] @ 0 / 393216   (overlay dead qkv)
  //   vb   bf16 [48][16384] @ 786432
  //   num  [4][49][16384] @ 1179648  (overlays dead qkv tail + dwq)
  //   tokT [48][16384] @ 4390912
  float* qkv = ws;
  float* dwq = ws + 2359296;
  unsigned short* qn = (unsigned short*)ws;
  unsigned short* kn = (unsigned short*)(ws + 393216);
  unsigned short* vb = (unsigned short*)(ws + 786432);
  float* num  = ws + 1179648;
  float* tokT = ws + 4390912;

  k_pointwise<<<dim3(64, 9), 256, 0, stream>>>(x, qkv_w, qkv);
  k_dwconv<<<dim3(64, 144), 256, 0, stream>>>(qkv, dw_w, dwq);
  k_norm<<<dim3(64, 1), 256, 0, stream>>>(dwq, temp, qn, kn, vb);
  k_attn<<<dim3(128, 4), 256, 0, stream>>>(qn, kn, vb, num);
  k_combine<<<dim3(64, 48), 256, 0, stream>>>(num, tokT);
  k_pointwise<<<dim3(64, 3), 256, 0, stream>>>(tokT, proj_w, (float*)d_out);
}